// Round 11
// baseline (241.548 us; speedup 1.0000x reference)
//
#include <hip/hip_runtime.h>
#include <hip/hip_bf16.h>

// MSAttention on MI355X. R11: non-attn chain rework — pre-convert x/w_in/w_pw to bf16 once
// (k_cvt4), make all GEMM staging pure 16B bf16 copies (no f2bf in K-loops), and raise mm
// grids to 512/512/256 blocks (were 256/256/128 at 1 block/CU). k_attn/k_dwconv/k_prep
// unchanged from R10 (228.3 us, absmax 0.1464844).
// ws layout (32 MB, time-shared):
//   @0     Y f32 [8][512][1024] 16 MB (mm_in->convs->prep)      then Ob bf16 [8192][512] 8 MB
//   @16    xb bf16 [8192][512] 8 MB (cvt->mm_in)  then tmp f32 4 MB (convs)
//                                                 then Vp bf16 [128][8][8][64][8] 8 MB (prep->attn)
//   @24    wib bf16 512 KB + wpwb bf16 32 KB (cvt->mm_in / ->pw3)
//                                                 then Qt bf16 [128][1024][32] 8 MB (prep->attn)

#define DIMM 512
#define NTOK 1024
#define CC   128
#define DD   32
#define BB   8
#define EPSB 1e-5f
#define SCALE_ATT 0.17677669529663687f   // 32^-0.5
#define K2EXP (SCALE_ATT * 1.4426950408889634f)  // scale * log2(e), folded into exp2
#define TJ 128

typedef __attribute__((ext_vector_type(8))) short short8;
typedef __attribute__((ext_vector_type(4))) float f32x4;

__device__ __forceinline__ unsigned short f2bf(float f) {
    unsigned int x = __float_as_uint(f);
    unsigned int r = x + 0x7fffu + ((x >> 16) & 1u);   // RNE, finite inputs
    return (unsigned short)(r >> 16);
}
__device__ __forceinline__ unsigned int f2bf2(float lo, float hi) {
    return (unsigned int)f2bf(lo) | ((unsigned int)f2bf(hi) << 16);
}

// ---------------- K0: f32->bf16 convert (x, w_in, w_pw) ----------------
#define CVT_NX (BB * NTOK * DIMM)   // 4194304
#define CVT_NW (DIMM * DIMM)        // 262144
#define CVT_NP (CC * CC)            // 16384
#define CVT_TOT4 ((CVT_NX + CVT_NW + CVT_NP) / 4)
__global__ __launch_bounds__(256) void k_cvt4(
    const float* __restrict__ x, const float* __restrict__ wi, const float* __restrict__ wp,
    unsigned short* __restrict__ xb, unsigned short* __restrict__ wib, unsigned short* __restrict__ wpwb)
{
    int idx = blockIdx.x * 256 + threadIdx.x;
    if (idx >= CVT_TOT4) return;
    int e = idx * 4;
    const float* src; unsigned short* dst; int off;
    if (e < CVT_NX)                 { src = x;  dst = xb;   off = e; }
    else if (e < CVT_NX + CVT_NW)   { src = wi; dst = wib;  off = e - CVT_NX; }
    else                            { src = wp; dst = wpwb; off = e - CVT_NX - CVT_NW; }
    float4 v = *(const float4*)&src[off];
    *(uint2*)&dst[off] = make_uint2(f2bf2(v.x, v.y), f2bf2(v.z, v.w));
}

// ---------------- K1: inconv GEMM (pure bf16) + BN1 ----------------
// Y[b][o][n] = BN1( sum_c w_in[o][c] * x[r][c] ), r = b*1024+n. grid (128 r-blocks, 4 o-blocks).
__global__ __launch_bounds__(256) void k_mm_in(
    const unsigned short* __restrict__ Wb,   // [512][512] bf16
    const unsigned short* __restrict__ Xb,   // [8192][512] bf16
    const float* __restrict__ g1, const float* __restrict__ b1,
    const float* __restrict__ m1, const float* __restrict__ v1,
    float* __restrict__ Y)
{
    __shared__ __align__(16) unsigned short As[128][72];   // [o][k]
    __shared__ __align__(16) unsigned short Bs[64][72];    // [r][k]
    const int r0 = blockIdx.x * 64;
    const int o0 = blockIdx.y * 128;
    const int b  = r0 >> 10, nloc0 = r0 & 1023;
    const int t = threadIdx.x, wid = t >> 6, lane = t & 63;
    const int l16 = lane & 15, quad = lane >> 4;
    const int wm = (wid >> 1) * 64, wn = (wid & 1) * 32;

    f32x4 acc[4][2];
#pragma unroll
    for (int i = 0; i < 4; i++) { acc[i][0] = (f32x4){0.f,0.f,0.f,0.f}; acc[i][1] = (f32x4){0.f,0.f,0.f,0.f}; }

    for (int k0 = 0; k0 < DIMM; k0 += 64) {
        __syncthreads();
#pragma unroll
        for (int it = 0; it < 4; it++) {
            int flat = it * 256 + t;             // 1024 short8-chunks
            int row = flat >> 3, c8 = flat & 7;
            *(short8*)&As[row][c8 * 8] = *(const short8*)&Wb[(size_t)(o0 + row) * DIMM + k0 + c8 * 8];
        }
#pragma unroll
        for (int it = 0; it < 2; it++) {
            int flat = it * 256 + t;             // 512 short8-chunks
            int row = flat >> 3, c8 = flat & 7;
            *(short8*)&Bs[row][c8 * 8] = *(const short8*)&Xb[(size_t)(r0 + row) * DIMM + k0 + c8 * 8];
        }
        __syncthreads();
#pragma unroll
        for (int kk = 0; kk < 2; kk++) {
            short8 af[4], bf_[2];
#pragma unroll
            for (int i = 0; i < 4; i++) af[i]  = *(const short8*)&As[wm + i * 16 + l16][kk * 32 + quad * 8];
#pragma unroll
            for (int j = 0; j < 2; j++) bf_[j] = *(const short8*)&Bs[wn + j * 16 + l16][kk * 32 + quad * 8];
#pragma unroll
            for (int i = 0; i < 4; i++)
#pragma unroll
                for (int j = 0; j < 2; j++)
                    acc[i][j] = __builtin_amdgcn_mfma_f32_16x16x32_bf16(af[i], bf_[j], acc[i][j], 0, 0, 0);
        }
    }
#pragma unroll
    for (int i = 0; i < 4; i++)
#pragma unroll
        for (int r = 0; r < 4; r++) {
            int o = o0 + wm + i * 16 + quad * 4 + r;
            float inv  = g1[o] / sqrtf(v1[o] + EPSB);
            float beta = b1[o] - m1[o] * inv;
#pragma unroll
            for (int j = 0; j < 2; j++) {
                int n = nloc0 + wn + j * 16 + l16;
                Y[((size_t)b * DIMM + o) * NTOK + n] = acc[i][j][r] * inv + beta;
            }
        }
}

// ---------------- K2: depthwise 3x3 (unchanged) ----------------
__global__ __launch_bounds__(256) void k_dwconv(
    const float* __restrict__ Y, const float* __restrict__ w_dw,
    float* __restrict__ tmp, int s)
{
    __shared__ float img[34][34];
    const int c = blockIdx.x;
    const int b = blockIdx.y;
    const int t = threadIdx.x;
    for (int i = t; i < 34 * 34; i += 256) (&img[0][0])[i] = 0.f;
    __syncthreads();
    const float* src0 = Y + ((size_t)b * DIMM + s * CC + c) * NTOK;
    const float* src1 = (s >= 2) ? (Y + ((size_t)b * DIMM + (s - 1) * CC + c) * NTOK) : nullptr;
    for (int p = t; p < NTOK; p += 256) {
        float v = src0[p];
        if (src1) v += src1[p];
        img[(p >> 5) + 1][(p & 31) + 1] = v;
    }
    __syncthreads();
    float w[9];
#pragma unroll
    for (int i = 0; i < 9; i++) w[i] = w_dw[c * 9 + i];
    for (int p = t; p < NTOK; p += 256) {
        int yy = p >> 5, xx = p & 31;
        float s0 = 0.f;
#pragma unroll
        for (int ky = 0; ky < 3; ky++)
#pragma unroll
            for (int kx = 0; kx < 3; kx++)
                s0 += img[yy + ky][xx + kx] * w[ky * 3 + kx];
        tmp[((size_t)b * CC + c) * NTOK + p] = s0;
    }
}

// ---------------- K3: pointwise 1x1 MFMA + BN2 (bf16 A, 64x64 tiles) ----------------
// grid (16 n-blocks, 2 o-blocks, 8 b).
__global__ __launch_bounds__(256) void k_mm_pw(
    const float* __restrict__ tmp, const unsigned short* __restrict__ Wpwb,  // [128][128] bf16
    const float* __restrict__ g2, const float* __restrict__ b2,
    const float* __restrict__ m2, const float* __restrict__ v2,
    float* __restrict__ Y, int s)
{
    __shared__ __align__(16) unsigned short As[64][72];   // [o][k]
    __shared__ __align__(16) unsigned short Bs[64][72];   // [n][k]
    const int n0 = blockIdx.x * 64;
    const int o0 = blockIdx.y * 64;
    const int b  = blockIdx.z;
    const int t = threadIdx.x, wid = t >> 6, lane = t & 63;
    const int l16 = lane & 15, quad = lane >> 4;
    const int wm = (wid >> 1) * 32, wn = (wid & 1) * 32;

    f32x4 acc[2][2];
#pragma unroll
    for (int i = 0; i < 2; i++) { acc[i][0] = (f32x4){0.f,0.f,0.f,0.f}; acc[i][1] = (f32x4){0.f,0.f,0.f,0.f}; }

    for (int k0 = 0; k0 < CC; k0 += 64) {
        __syncthreads();
#pragma unroll
        for (int it = 0; it < 2; it++) {
            int flat = it * 256 + t;             // 512 short8-chunks
            int row = flat >> 3, c8 = flat & 7;
            *(short8*)&As[row][c8 * 8] = *(const short8*)&Wpwb[(size_t)(o0 + row) * CC + k0 + c8 * 8];
        }
#pragma unroll
        for (int it = 0; it < 4; it++) {         // B: tmp[c][n] f32 -> Bs[n][c] bf16 transpose
            int flat = it * 256 + t;
            int c = flat >> 4, n4 = (flat & 15) * 4;
            float4 v = *(const float4*)&tmp[((size_t)b * CC + k0 + c) * NTOK + n0 + n4];
            Bs[n4 + 0][c] = f2bf(v.x);
            Bs[n4 + 1][c] = f2bf(v.y);
            Bs[n4 + 2][c] = f2bf(v.z);
            Bs[n4 + 3][c] = f2bf(v.w);
        }
        __syncthreads();
#pragma unroll
        for (int kk = 0; kk < 2; kk++) {
            short8 af[2], bf_[2];
#pragma unroll
            for (int i = 0; i < 2; i++) af[i]  = *(const short8*)&As[wm + i * 16 + l16][kk * 32 + quad * 8];
#pragma unroll
            for (int j = 0; j < 2; j++) bf_[j] = *(const short8*)&Bs[wn + j * 16 + l16][kk * 32 + quad * 8];
#pragma unroll
            for (int i = 0; i < 2; i++)
#pragma unroll
                for (int j = 0; j < 2; j++)
                    acc[i][j] = __builtin_amdgcn_mfma_f32_16x16x32_bf16(af[i], bf_[j], acc[i][j], 0, 0, 0);
        }
    }
#pragma unroll
    for (int i = 0; i < 2; i++)
#pragma unroll
        for (int r = 0; r < 4; r++) {
            int o = o0 + wm + i * 16 + quad * 4 + r;
            float inv  = g2[o] / sqrtf(v2[o] + EPSB);
            float beta = b2[o] - m2[o] * inv;
#pragma unroll
            for (int j = 0; j < 2; j++) {
                int n = n0 + wn + j * 16 + l16;
                Y[((size_t)b * DIMM + s * CC + o) * NTOK + n] = acc[i][j][r] * inv + beta;
            }
        }
}

// ---------------- K3.5: prep — Y f32 -> Qt (token-major bf16) + Vp (PV A-frag order) ----------
__global__ __launch_bounds__(256) void k_prep(
    const float* __restrict__ Y,
    unsigned short* __restrict__ Vp,    // [128][8][8][64][8]
    unsigned short* __restrict__ Qt)    // [128][1024][32]
{
    __shared__ float T[32][129];
    const int jt = blockIdx.x;
    const int n0 = jt * 128;
    const int g  = blockIdx.y;
    const int b = g >> 4, s = (g >> 2) & 3, h = g & 3;
    const int cb = s * CC + h * DD;
    const int t = threadIdx.x;
#pragma unroll
    for (int k = 0; k < 8; k++) {
        int idx = k * 256 + t;
        int d = idx >> 6, jp = (idx & 63) * 2;
        float2 v = *(const float2*)&Y[((size_t)b * DIMM + cb + d) * NTOK + n0 + jp];
        T[d][jp] = v.x; T[d][jp + 1] = v.y;
    }
    __syncthreads();
#pragma unroll
    for (int k = 0; k < 8; k++) {
        int idx = k * 256 + t;
        int n = idx >> 4, dp = (idx & 15) * 2;
        *(unsigned int*)&Qt[((size_t)g * NTOK + n0 + n) * DD + dp] = f2bf2(T[dp][n], T[dp + 1][n]);
    }
#pragma unroll
    for (int e2 = 0; e2 < 2; e2++) {
        int e = e2 * 256 + t;
        int sub = e >> 6, lane = e & 63;
        int quad = lane >> 4, l16 = lane & 15;
        int d  = (sub & 1) * 16 + l16;
        int jb = (sub >> 1) * 32 + quad * 4;
        uint4 v;
        v.x = f2bf2(T[d][jb + 0],  T[d][jb + 1]);
        v.y = f2bf2(T[d][jb + 2],  T[d][jb + 3]);
        v.z = f2bf2(T[d][jb + 16], T[d][jb + 17]);
        v.w = f2bf2(T[d][jb + 18], T[d][jb + 19]);
        *(uint4*)&Vp[((((size_t)g * 8 + jt) * 8 + sub) * 64 + lane) * 8] = v;
    }
}

// ---------------- K4: register-only MFMA flash attention (unchanged from R10) ----------------
__global__ __launch_bounds__(256) void k_attn(
    const unsigned short* __restrict__ Qtg,
    const unsigned short* __restrict__ Vp,
    unsigned short* __restrict__ Ob)
{
    const int blk = blockIdx.x;
    const int g = blk & 127, ib = blk >> 7;
    const int b = g >> 4, s = (g >> 2) & 3, h = g & 3;
    const int cb = s * CC + h * DD;
    const unsigned short* Qt = Qtg + (size_t)g * NTOK * DD;          // [token][d]
    const unsigned short* Vg = Vp + (size_t)g * 8 * 8 * 64 * 8;      // [jt][sub][lane][8]
    const int t = threadIdx.x;
    const int wid = t >> 6, lane = t & 63;
    const int l16 = lane & 15, quad = lane >> 4;
    const int i = ib * 64 + wid * 16 + l16;      // this lane's token column

    const short8 qi = *(const short8*)&Qt[(size_t)i * DD + quad * 8];
    const short8 ones = {0x3F80, 0x3F80, 0x3F80, 0x3F80, 0x3F80, 0x3F80, 0x3F80, 0x3F80};

    float m_run = -INFINITY;
    f32x4 lacc = {0.f, 0.f, 0.f, 0.f};
    f32x4 oacc[2] = {{0.f,0.f,0.f,0.f},{0.f,0.f,0.f,0.f}};
    const f32x4 zero4 = {0.f, 0.f, 0.f, 0.f};

#pragma unroll 2
    for (int jt = 0; jt < 8; jt++) {
        const int j0 = jt * TJ;
        f32x4 sacc[8];
#pragma unroll
        for (int jb = 0; jb < 8; jb++) {
            short8 qj = *(const short8*)&Qt[(size_t)(j0 + jb * 16 + l16) * DD + quad * 8];
            sacc[jb] = __builtin_amdgcn_mfma_f32_16x16x32_bf16(qj, qi, zero4, 0, 0, 0);
        }
        float mx = fmaxf(fmaxf(sacc[0][0], sacc[0][1]), fmaxf(sacc[0][2], sacc[0][3]));
#pragma unroll
        for (int jb = 1; jb < 8; jb++) {
            float m2_ = fmaxf(fmaxf(sacc[jb][0], sacc[jb][1]), fmaxf(sacc[jb][2], sacc[jb][3]));
            mx = fmaxf(mx, m2_);
        }
        mx = fmaxf(mx, __shfl_xor(mx, 16));
        mx = fmaxf(mx, __shfl_xor(mx, 32));

        float mn = fmaxf(m_run, mx);
        float al = exp2f((m_run - mn) * K2EXP);   // 0 on first tile
        m_run = mn;
        float mnk = mn * K2EXP;

        short8 pb[4];
#pragma unroll
        for (int jb = 0; jb < 8; jb++) {
            float p0 = exp2f(fmaf(sacc[jb][0], K2EXP, -mnk));
            float p1 = exp2f(fmaf(sacc[jb][1], K2EXP, -mnk));
            float p2 = exp2f(fmaf(sacc[jb][2], K2EXP, -mnk));
            float p3 = exp2f(fmaf(sacc[jb][3], K2EXP, -mnk));
            ((unsigned int*)&pb[jb >> 1])[(jb & 1) * 2]     =
                __builtin_amdgcn_perm(__float_as_uint(p1), __float_as_uint(p0), 0x07060302u);
            ((unsigned int*)&pb[jb >> 1])[(jb & 1) * 2 + 1] =
                __builtin_amdgcn_perm(__float_as_uint(p3), __float_as_uint(p2), 0x07060302u);
        }

#pragma unroll
        for (int r = 0; r < 4; r++) { oacc[0][r] *= al; oacc[1][r] *= al; lacc[r] *= al; }

#pragma unroll
        for (int wp = 0; wp < 4; wp++) {
            short8 af0 = *(const short8*)&Vg[(((size_t)jt * 8 + wp * 2 + 0) * 64 + lane) * 8];
            short8 af1 = *(const short8*)&Vg[(((size_t)jt * 8 + wp * 2 + 1) * 64 + lane) * 8];
            oacc[0] = __builtin_amdgcn_mfma_f32_16x16x32_bf16(af0, pb[wp], oacc[0], 0, 0, 0);
            oacc[1] = __builtin_amdgcn_mfma_f32_16x16x32_bf16(af1, pb[wp], oacc[1], 0, 0, 0);
            lacc    = __builtin_amdgcn_mfma_f32_16x16x32_bf16(ones, pb[wp], lacc, 0, 0, 0);
        }
    }

    float invl = 1.f / lacc[0];
#pragma unroll
    for (int dblk = 0; dblk < 2; dblk++) {
        uint2 pkd;
        pkd.x = f2bf2(oacc[dblk][0] * invl, oacc[dblk][1] * invl);
        pkd.y = f2bf2(oacc[dblk][2] * invl, oacc[dblk][3] * invl);
        *(uint2*)&Ob[((size_t)b * NTOK + i) * DIMM + cb + dblk * 16 + quad * 4] = pkd;
    }
}

// ---------------- K5: out-proj GEMM (A=Ob bf16, B=w_out f32 inline-cvt), f32 out ----------
// grid (64 r-blocks, 8 o-blocks): r-tile 128, o-tile 64.
__global__ __launch_bounds__(256) void k_mm_out(
    const unsigned short* __restrict__ Oin,  // [8192][512] bf16
    const float* __restrict__ w_out,         // [512][512] f32
    float* __restrict__ out)
{
    __shared__ __align__(16) unsigned short As[128][72];  // [r][k]
    __shared__ __align__(16) unsigned short Bs[64][72];   // [o][k]
    const int r0 = blockIdx.x * 128;
    const int o0 = blockIdx.y * 64;
    const int t = threadIdx.x, wid = t >> 6, lane = t & 63;
    const int l16 = lane & 15, quad = lane >> 4;
    const int wm = (wid >> 1) * 64, wn = (wid & 1) * 32;

    f32x4 acc[4][2];
#pragma unroll
    for (int i = 0; i < 4; i++) { acc[i][0] = (f32x4){0.f,0.f,0.f,0.f}; acc[i][1] = (f32x4){0.f,0.f,0.f,0.f}; }

    for (int k0 = 0; k0 < DIMM; k0 += 64) {
        __syncthreads();
#pragma unroll
        for (int it = 0; it < 4; it++) {
            int flat = it * 256 + t;             // 1024 short8-chunks
            int row = flat >> 3, c8 = flat & 7;
            *(short8*)&As[row][c8 * 8] = *(const short8*)&Oin[(size_t)(r0 + row) * DIMM + k0 + c8 * 8];
        }
#pragma unroll
        for (int it = 0; it < 4; it++) {         // 1024 float4-chunks, inline cvt (w_out is small)
            int flat = it * 256 + t;
            int row = flat >> 4, c4 = flat & 15;
            float4 w4 = *(const float4*)&w_out[(size_t)(o0 + row) * DIMM + k0 + c4 * 4];
            *(uint2*)&Bs[row][c4 * 4] = make_uint2(f2bf2(w4.x, w4.y), f2bf2(w4.z, w4.w));
        }
        __syncthreads();
#pragma unroll
        for (int kk = 0; kk < 2; kk++) {
            short8 af[4], bf_[2];
#pragma unroll
            for (int i = 0; i < 4; i++) af[i]  = *(const short8*)&As[wm + i * 16 + l16][kk * 32 + quad * 8];
#pragma unroll
            for (int j = 0; j < 2; j++) bf_[j] = *(const short8*)&Bs[wn + j * 16 + l16][kk * 32 + quad * 8];
#pragma unroll
            for (int i = 0; i < 4; i++)
#pragma unroll
                for (int j = 0; j < 2; j++)
                    acc[i][j] = __builtin_amdgcn_mfma_f32_16x16x32_bf16(af[i], bf_[j], acc[i][j], 0, 0, 0);
        }
    }
#pragma unroll
    for (int i = 0; i < 4; i++)
#pragma unroll
        for (int r = 0; r < 4; r++) {
            int rr = r0 + wm + i * 16 + quad * 4 + r;
#pragma unroll
            for (int j = 0; j < 2; j++) {
                int o = o0 + wn + j * 16 + l16;
                out[(size_t)rr * DIMM + o] = acc[i][j][r];
            }
        }
}

extern "C" void kernel_launch(void* const* d_in, const int* in_sizes, int n_in,
                              void* d_out, int out_size, void* d_ws, size_t ws_size,
                              hipStream_t stream)
{
    const float* x    = (const float*)d_in[0];
    const float* w_in = (const float*)d_in[1];
    const float* g1   = (const float*)d_in[2];
    const float* b1   = (const float*)d_in[3];
    const float* m1   = (const float*)d_in[4];
    const float* v1   = (const float*)d_in[5];
    const float* wdw  = (const float*)d_in[6];
    const float* wpw  = (const float*)d_in[7];
    const float* g2   = (const float*)d_in[8];
    const float* b2   = (const float*)d_in[9];
    const float* m2   = (const float*)d_in[10];
    const float* v2   = (const float*)d_in[11];
    const float* wout = (const float*)d_in[12];
    float* out = (float*)d_out;

    char* base = (char*)d_ws;
    float*          Y    = (float*)base;                                  // 16 MB (dies at prep)
    unsigned short* Ob   = (unsigned short*)base;                         // 8 MB  (attn out, over Y)
    unsigned short* xb   = (unsigned short*)(base + (size_t)16 * 1024 * 1024); // 8 MB (cvt->mm_in)
    float*          tmp  = (float*)(base + (size_t)16 * 1024 * 1024);     // 4 MB (convs, over dead xb)
    unsigned short* Vp   = (unsigned short*)(base + (size_t)16 * 1024 * 1024); // 8 MB (prep, over dead tmp)
    unsigned short* wib  = (unsigned short*)(base + (size_t)24 * 1024 * 1024); // 512 KB (cvt->mm_in)
    unsigned short* wpwb = (unsigned short*)(base + (size_t)24 * 1024 * 1024 + 524288); // 32 KB (->pw3)
    unsigned short* Qt   = (unsigned short*)(base + (size_t)24 * 1024 * 1024); // 8 MB (prep, over dead wib/wpwb)

    k_cvt4<<<dim3((CVT_TOT4 + 255) / 256), 256, 0, stream>>>(x, w_in, wpw, xb, wib, wpwb);
    k_mm_in<<<dim3(128, 4), 256, 0, stream>>>(wib, xb, g1, b1, m1, v1, Y);
    for (int s = 1; s <= 3; s++) {
        k_dwconv<<<dim3(CC, BB), 256, 0, stream>>>(Y, wdw, tmp, s);
        k_mm_pw<<<dim3(16, 2, 8), 256, 0, stream>>>(tmp, wpwb, g2, b2, m2, v2, Y, s);
    }
    k_prep<<<dim3(8, 128), 256, 0, stream>>>(Y, Vp, Qt);
    k_attn<<<dim3(2048), 256, 0, stream>>>(Qt, Vp, Ob);
    k_mm_out<<<dim3(64, 8), 256, 0, stream>>>(Ob, wout, out);
}